// Round 6
// baseline (305587.524 us; speedup 1.0000x reference)
//
#include <hip/hip_runtime.h>
#include <hip/hip_bf16.h>

#define NMEL 80

typedef unsigned u32x4 __attribute__((ext_vector_type(4)));

__device__ __forceinline__ float bf2f(unsigned short u) {
  unsigned v = ((unsigned)u) << 16; float f; __builtin_memcpy(&f, &v, 4); return f;
}
__device__ __forceinline__ unsigned short f2bf_u(float f) {
  __hip_bfloat16 h = __float2bfloat16(f); unsigned short u; __builtin_memcpy(&u, &h, 2); return u;
}
__device__ __forceinline__ void unpk(unsigned u, float& lo, float& hi) {
  unsigned l = u << 16, h = u & 0xffff0000u;
  __builtin_memcpy(&lo, &l, 4); __builtin_memcpy(&hi, &h, 4);
}

// ---------------- workspace layout (bytes) ----------------
constexpr size_t OFF_ATTNR = 0;                                  // bf16 pairs, attn_gemm layout
constexpr size_t SZ_ATTNR = (size_t)64 * 1024 * 256 * 2;         // 33,554,432
constexpr size_t OFF_ENCP = OFF_ATTNR + SZ_ATTNR;                // uint4[(b*32+d8)*1024+te]
constexpr size_t SZ_ENCP = (size_t)64 * 1024 * 256 * 2;          // 33,554,432
constexpr size_t OFF_PRE2 = OFF_ENCP + SZ_ENCP;                  // bf16 [64000][256]
constexpr size_t SZ_PRE2 = (size_t)64000 * 256 * 2;
constexpr size_t OFF_WDT = OFF_PRE2 + SZ_PRE2;                   // f32 float4[kq][256]
constexpr size_t SZ_WDT = (size_t)65536 * 4;
constexpr size_t OFF_WHT = OFF_WDT + SZ_WDT;                     // f32 float4[kq][1024]
constexpr size_t SZ_W1M = (size_t)262144 * 4;
constexpr size_t OFF_WCT = OFF_WHT + SZ_W1M;
constexpr size_t OFF_WPT = OFF_WCT + SZ_W1M;
constexpr size_t OFF_BIASG = OFF_WPT + SZ_W1M;                   // f32 [1024]
constexpr size_t SZ_BIASG = 1024 * 4;
constexpr size_t WS_NEED = OFF_BIASG + SZ_BIASG;                 // ~98.5 MiB

// ---------------- enc fp32 -> bf16-packed [b][d8][te] uint4 ----------------
__global__ __launch_bounds__(256) void conv_encP(const float* __restrict__ enc,
                                                 u32x4* __restrict__ encP) {
  int idx = blockIdx.x * 256 + threadIdx.x;      // 64*32*1024 = 2,097,152 exact
  int b = idx >> 15, r = idx & 32767;
  int d8 = r >> 10, te = r & 1023;
  const float4* src = (const float4*)(enc + ((size_t)(b * 1024 + te)) * 256 + d8 * 8);
  float4 x0 = src[0], x1 = src[1];
  u32x4 o;
  o.x = (unsigned)f2bf_u(x0.x) | ((unsigned)f2bf_u(x0.y) << 16);
  o.y = (unsigned)f2bf_u(x0.z) | ((unsigned)f2bf_u(x0.w) << 16);
  o.z = (unsigned)f2bf_u(x1.x) | ((unsigned)f2bf_u(x1.y) << 16);
  o.w = (unsigned)f2bf_u(x1.z) | ((unsigned)f2bf_u(x1.w) << 16);
  encP[((size_t)(b * 32 + d8)) * 1024 + te] = o;
}

// ---------------- weight re-layout (fp32, row-coalesced float4) ----------------
__global__ __launch_bounds__(256) void prep_w2(
    const float* __restrict__ W_dec, const float* __restrict__ W_hh,
    const float* __restrict__ W_ih, const float* __restrict__ b_ih,
    const float* __restrict__ b_hh,
    float* __restrict__ WdT, float* __restrict__ WhT,
    float* __restrict__ WcT, float* __restrict__ WpT, float* __restrict__ biasG) {
  int idx = blockIdx.x * 256 + threadIdx.x;
  if (idx < 65536) {                       // WdT[kq][a][q] = W_dec[a][4kq+q]
    int q = idx & 3, a = (idx >> 2) & 255, kq = idx >> 10;
    WdT[idx] = W_dec[(size_t)a * 256 + kq * 4 + q];
  } else if (idx < 327680) {               // WhT[kq][g][q] = W_hh[g][4kq+q]
    int i = idx - 65536;
    int q = i & 3, g = (i >> 2) & 1023, kq = i >> 12;
    WhT[i] = W_hh[(size_t)g * 256 + kq * 4 + q];
  } else if (idx < 589824) {               // WcT: ctx part of W_ih (cols 256..511)
    int i = idx - 327680;
    int q = i & 3, g = (i >> 2) & 1023, kq = i >> 12;
    WcT[i] = W_ih[(size_t)g * 512 + 256 + kq * 4 + q];
  } else if (idx < 851968) {               // WpT: prenet part of W_ih (cols 0..255)
    int i = idx - 589824;
    int q = i & 3, g = (i >> 2) & 1023, kq = i >> 12;
    WpT[i] = W_ih[(size_t)g * 512 + kq * 4 + q];
  } else if (idx < 852992) {
    int g = idx - 851968;
    biasG[g] = b_ih[g] + b_hh[g];
  }
}

// ---------------- attn_enc GEMM -> bf16 layout attnR (unchanged) ----------------
__global__ __launch_bounds__(256) void attn_gemm(const float* __restrict__ enc,
                                                 const float* __restrict__ W_enc,
                                                 const float* __restrict__ b_enc,
                                                 unsigned* __restrict__ attnR) {
  __shared__ unsigned short Alds[64 * 260];
  const int tid = threadIdx.x;
  const int row0 = blockIdx.x * 64;
  const int wv = tid >> 6, lane = tid & 63, nb = wv * 64;
  for (int idx = tid; idx < 64 * 256; idx += 256) {
    int r = idx >> 8, k = idx & 255;
    Alds[r * 260 + k] = f2bf_u(enc[(size_t)(row0 + r) * 256 + k]);
  }
  __syncthreads();
  float acc[64];
#pragma unroll
  for (int n = 0; n < 64; ++n) acc[n] = b_enc[nb + n];
  for (int k8 = 0; k8 < 256; k8 += 8) {
    ushort4 ua = *(const ushort4*)&Alds[lane * 260 + k8];
    ushort4 ub = *(const ushort4*)&Alds[lane * 260 + k8 + 4];
    float a0 = bf2f(ua.x), a1 = bf2f(ua.y), a2 = bf2f(ua.z), a3 = bf2f(ua.w);
    float a4 = bf2f(ub.x), a5 = bf2f(ub.y), a6 = bf2f(ub.z), a7 = bf2f(ub.w);
#pragma unroll
    for (int n = 0; n < 64; ++n) {
      const float4* wp = (const float4*)(W_enc + (size_t)(nb + n) * 256 + k8);
      float4 w0 = wp[0], w1 = wp[1];
      acc[n] = fmaf(a0, w0.x, acc[n]); acc[n] = fmaf(a1, w0.y, acc[n]);
      acc[n] = fmaf(a2, w0.z, acc[n]); acc[n] = fmaf(a3, w0.w, acc[n]);
      acc[n] = fmaf(a4, w1.x, acc[n]); acc[n] = fmaf(a5, w1.y, acc[n]);
      acc[n] = fmaf(a6, w1.z, acc[n]); acc[n] = fmaf(a7, w1.w, acc[n]);
    }
  }
  const float CE = 2.8853900817779268f;  // 2*log2(e)
  const int b = row0 >> 10;
  const int te_g = (row0 & 1023) + lane;
  const int sl = te_g >> 8, te_loc = te_g & 255;
#pragma unroll
  for (int n = 0; n < 64; n += 2) {
    int a = nb + n;
    unsigned pair = (unsigned)f2bf_u(acc[n] * CE) | ((unsigned)f2bf_u(acc[n + 1] * CE) << 16);
    size_t u4 = ((((size_t)(b * 4 + sl) * 4 + (a >> 6)) * 8 + ((a >> 3) & 7)) * 256 + te_loc);
    attnR[u4 * 4 + ((a & 7) >> 1)] = pair;
  }
}

// ---------------- fused prenet (unchanged) ----------------
__global__ __launch_bounds__(256) void prenet_fused(const float* __restrict__ tmel,
                                                    const float* __restrict__ W1,
                                                    const float* __restrict__ b1,
                                                    const float* __restrict__ W2,
                                                    const float* __restrict__ b2,
                                                    unsigned short* __restrict__ pre2) {
  __shared__ unsigned short Alds[64 * 260];
  const int tid = threadIdx.x;
  const int row0 = blockIdx.x * 64;
  const int wv = tid >> 6, lane = tid & 63, nb = wv * 64;
  for (int idx = tid; idx < 64 * 80; idx += 256) {
    int r = idx / 80, k = idx - r * 80;
    int R = row0 + r;
    float v = (R % 1000 != 0) ? tmel[(size_t)(R - 1) * NMEL + k] : 0.f;
    Alds[r * 260 + k] = f2bf_u(v);
  }
  __syncthreads();
  float acc[64];
#pragma unroll
  for (int n = 0; n < 64; ++n) acc[n] = b1[nb + n];
  for (int k8 = 0; k8 < 80; k8 += 8) {
    ushort4 ua = *(const ushort4*)&Alds[lane * 260 + k8];
    ushort4 ub = *(const ushort4*)&Alds[lane * 260 + k8 + 4];
    float a0 = bf2f(ua.x), a1 = bf2f(ua.y), a2 = bf2f(ua.z), a3 = bf2f(ua.w);
    float a4 = bf2f(ub.x), a5 = bf2f(ub.y), a6 = bf2f(ub.z), a7 = bf2f(ub.w);
#pragma unroll
    for (int n = 0; n < 64; ++n) {
      const float4* wp = (const float4*)(W1 + (size_t)(nb + n) * 80 + k8);
      float4 w0 = wp[0], w1 = wp[1];
      acc[n] = fmaf(a0, w0.x, acc[n]); acc[n] = fmaf(a1, w0.y, acc[n]);
      acc[n] = fmaf(a2, w0.z, acc[n]); acc[n] = fmaf(a3, w0.w, acc[n]);
      acc[n] = fmaf(a4, w1.x, acc[n]); acc[n] = fmaf(a5, w1.y, acc[n]);
      acc[n] = fmaf(a6, w1.z, acc[n]); acc[n] = fmaf(a7, w1.w, acc[n]);
    }
  }
  __syncthreads();
#pragma unroll
  for (int n = 0; n < 64; ++n) Alds[lane * 260 + nb + n] = f2bf_u(fmaxf(acc[n], 0.f));
  __syncthreads();
#pragma unroll
  for (int n = 0; n < 64; ++n) acc[n] = b2[nb + n];
  for (int k8 = 0; k8 < 256; k8 += 8) {
    ushort4 ua = *(const ushort4*)&Alds[lane * 260 + k8];
    ushort4 ub = *(const ushort4*)&Alds[lane * 260 + k8 + 4];
    float a0 = bf2f(ua.x), a1 = bf2f(ua.y), a2 = bf2f(ua.z), a3 = bf2f(ua.w);
    float a4 = bf2f(ub.x), a5 = bf2f(ub.y), a6 = bf2f(ub.z), a7 = bf2f(ub.w);
#pragma unroll
    for (int n = 0; n < 64; ++n) {
      const float4* wp = (const float4*)(W2 + (size_t)(nb + n) * 256 + k8);
      float4 w0 = wp[0], w1 = wp[1];
      acc[n] = fmaf(a0, w0.x, acc[n]); acc[n] = fmaf(a1, w0.y, acc[n]);
      acc[n] = fmaf(a2, w0.z, acc[n]); acc[n] = fmaf(a3, w0.w, acc[n]);
      acc[n] = fmaf(a4, w1.x, acc[n]); acc[n] = fmaf(a5, w1.y, acc[n]);
      acc[n] = fmaf(a6, w1.z, acc[n]); acc[n] = fmaf(a7, w1.w, acc[n]);
    }
  }
  __syncthreads();
#pragma unroll
  for (int n = 0; n < 64; ++n) Alds[lane * 260 + nb + n] = f2bf_u(fmaxf(acc[n], 0.f));
  __syncthreads();
  for (int idx = tid; idx < 64 * 128; idx += 256) {
    int r = idx >> 7, k2 = (idx & 127) * 2;
    unsigned pair = (unsigned)Alds[r * 260 + k2] | ((unsigned)Alds[r * 260 + k2 + 1] << 16);
    *(unsigned*)(pre2 + (size_t)(row0 + r) * 256 + k2) = pair;
  }
}

// ---------------- single-WG-per-batch persistent decoder ----------------
// 64 WGs x 1024 threads. Register discipline: every phase keeps peak live <= ~55 VGPRs
// so the compiler's 64-VGPR choice holds WITHOUT spilling (rounds 0-5: spill traffic
// 6.7 GB/dispatch + weight L2 eviction). Explicit 8-deep (P3) / 4-deep (P5) load
// batching restores memory-level parallelism inside that envelope. Ctx partials are
// reduced in-wave via shfl_xor (kills the 33 KB LDS array + serial P6 row walk).
__global__ __launch_bounds__(1024) void decoder_one(
    const u32x4* __restrict__ attnR, const u32x4* __restrict__ encP,
    const unsigned short* __restrict__ pre2,
    const float4* __restrict__ WdT, const float4* __restrict__ WhT,
    const float4* __restrict__ WcT, const float4* __restrict__ WpT,
    const float* __restrict__ biasG,
    const float* __restrict__ b_dec, const float* __restrict__ v_w,
    const float* __restrict__ v_b, const float* __restrict__ enc_mask,
    const float* __restrict__ mel_W, const float* __restrict__ mel_b,
    const float* __restrict__ stop_W, const float* __restrict__ stop_b,
    float* __restrict__ out) {
  __shared__ __align__(16) float scratchB[4096];   // P1 dec partials / P3 energy partials
  __shared__ __align__(16) float p_lds[1024];
  __shared__ __align__(16) float gates_lds[1024];
  __shared__ __align__(16) float h_lds[256];
  __shared__ __align__(16) float ctx_lds[256];
  __shared__ __align__(16) float ctxp_lds[256];
  __shared__ __align__(16) float pre_lds[256];
  __shared__ __align__(16) float dec_lds[256];
  __shared__ __align__(16) float v2_lds[256];
  __shared__ float red_lds[16];

  const int tid = threadIdx.x;
  const int b = blockIdx.x;                 // one batch per WG
  const int t8 = tid & 255, chunk = tid >> 8;
  const int lane = tid & 63, wid = tid >> 6;
  const int d8 = tid >> 5, tec = tid & 31;  // context-phase mapping
  const float CE = 2.8853900817779268f;     // 2*log2(e)
  const float L2E = 1.4426950408889634f;    // log2(e)

  // ---- init ----
  if (tid < 256) {
    h_lds[tid] = 0.f;
    float v = v_w[tid];
    v2_lds[tid] = -2.f * v;
    for (int m = 32; m; m >>= 1) v += __shfl_xor(v, m);
    if (lane == 0) red_lds[wid] = v;
  }
  float c_reg = 0.f;
  const float maskv = enc_mask[b * 1024 + tid];
  const float bdec_r = (tid < 256) ? b_dec[tid] : 0.f;
  const float biasg_r = biasG[tid];
  const float melb_r = (tid < 640 && (tid & 7) == 0) ? mel_b[tid >> 3] : 0.f;
  float stopw[8];
  if (wid == 11) {
#pragma unroll
    for (int i = 0; i < 8; ++i) stopw[i] = stop_W[lane * 8 + i];
  }
  __syncthreads();
  const float Sv_vb = red_lds[0] + red_lds[1] + red_lds[2] + red_lds[3] + v_b[0];
  const float stopb0 = stop_b[0];

  const u32x4* aB = attnR + (size_t)b * 32768 + chunk * 2048 + t8;
  const u32x4* eB = encP + ((size_t)(b * 32 + d8)) * 1024 + tec;
  const float4* wdB = WdT + chunk * 16 * 256 + t8;
  const float4* whB = WhT + tid;
  const float4* wcB = WcT + tid;
  const float4* wpB = WpT + tid;
  const unsigned short* pre2_b = pre2 + (size_t)b * 256000;
  float* outm = out + (size_t)b * 80000;
  float* outs = out + (size_t)5120000 + b * 1000;

  auto heads = [&](int ith) {  // mel + stop for step ith (uses h_lds, ctx_lds)
    if (tid < 640) {
      const int m = tid >> 3, q = tid & 7;
      float acc = melb_r;
      const float4* wm = (const float4*)(mel_W + (size_t)m * 512 + q * 64);
      const float4* xp = (q < 4) ? (const float4*)&h_lds[q * 64]
                                 : (const float4*)&ctx_lds[(q - 4) * 64];
#pragma unroll
      for (int i = 0; i < 16; ++i) {
        float4 w = wm[i]; float4 x = xp[i];
        acc = fmaf(w.x, x.x, acc); acc = fmaf(w.y, x.y, acc);
        acc = fmaf(w.z, x.z, acc); acc = fmaf(w.w, x.w, acc);
      }
      acc += __shfl_xor(acc, 1); acc += __shfl_xor(acc, 2); acc += __shfl_xor(acc, 4);
      if (q == 0) outm[ith * 80 + m] = acc;
    } else if (wid == 11) {
      float acc = 0.f;
#pragma unroll
      for (int i = 0; i < 8; ++i) {
        int cc = lane * 8 + i;
        float x = (cc < 256) ? h_lds[cc] : ctx_lds[cc - 256];
        acc = fmaf(stopw[i], x, acc);
      }
      for (int m = 32; m; m >>= 1) acc += __shfl_xor(acc, m);
      if (lane == 0) outs[ith] = acc + stopb0;
    }
  };

  float gph = 0.f;  // gates partial (bias + pre-dot + h-dot), carried P5 -> P7

  for (int it = 0; it < 1000; ++it) {
    // ---- P1: attn_dec partials (uses h from prev step) + pre load + heads(it-1) ----
    {
      float acc = 0.f;
#pragma unroll
      for (int i = 0; i < 16; ++i) {
        float4 w = wdB[(size_t)i << 8];
        float4 h4 = *(const float4*)&h_lds[chunk * 64 + i * 4];
        acc = fmaf(w.x, h4.x, acc); acc = fmaf(w.y, h4.y, acc);
        acc = fmaf(w.z, h4.z, acc); acc = fmaf(w.w, h4.w, acc);
      }
      scratchB[(chunk << 8) + t8] = acc;
      if (tid < 256) pre_lds[tid] = bf2f(pre2_b[it * 256 + tid]);
      if (it > 0) heads(it - 1);
    }
    __syncthreads();
    // ---- P2: dec reduce (pre-scaled by 2*log2e) ----
    if (tid < 256)
      dec_lds[tid] = (bdec_r + scratchB[tid] + scratchB[256 + tid] +
                      scratchB[512 + tid] + scratchB[768 + tid]) * CE;
    __syncthreads();
    // ---- P3: energy partials (attn nt-stream, 8 loads in flight per wave) ----
    {
      auto consume = [&](u32x4 u, int j, float& acc) {
        int ab = (chunk << 6) + (j << 3);
        float4 d0 = *(const float4*)&dec_lds[ab];
        float4 d1 = *(const float4*)&dec_lds[ab + 4];
        float4 v0 = *(const float4*)&v2_lds[ab];
        float4 v1 = *(const float4*)&v2_lds[ab + 4];
        float t0, t1, t2, t3, t4, t5, t6, t7;
        unpk(u.x, t0, t1); unpk(u.y, t2, t3); unpk(u.z, t4, t5); unpk(u.w, t6, t7);
        acc = fmaf(v0.x, __builtin_amdgcn_rcpf(1.f + __builtin_amdgcn_exp2f(t0 + d0.x)), acc);
        acc = fmaf(v0.y, __builtin_amdgcn_rcpf(1.f + __builtin_amdgcn_exp2f(t1 + d0.y)), acc);
        acc = fmaf(v0.z, __builtin_amdgcn_rcpf(1.f + __builtin_amdgcn_exp2f(t2 + d0.z)), acc);
        acc = fmaf(v0.w, __builtin_amdgcn_rcpf(1.f + __builtin_amdgcn_exp2f(t3 + d0.w)), acc);
        acc = fmaf(v1.x, __builtin_amdgcn_rcpf(1.f + __builtin_amdgcn_exp2f(t4 + d1.x)), acc);
        acc = fmaf(v1.y, __builtin_amdgcn_rcpf(1.f + __builtin_amdgcn_exp2f(t5 + d1.y)), acc);
        acc = fmaf(v1.z, __builtin_amdgcn_rcpf(1.f + __builtin_amdgcn_exp2f(t6 + d1.z)), acc);
        acc = fmaf(v1.w, __builtin_amdgcn_rcpf(1.f + __builtin_amdgcn_exp2f(t7 + d1.w)), acc);
      };
#pragma unroll 1
      for (int sl = 0; sl < 4; ++sl) {
        const u32x4* ap = aB + sl * 8192;
        u32x4 u0 = __builtin_nontemporal_load(&ap[0 * 256]);
        u32x4 u1 = __builtin_nontemporal_load(&ap[1 * 256]);
        u32x4 u2 = __builtin_nontemporal_load(&ap[2 * 256]);
        u32x4 u3 = __builtin_nontemporal_load(&ap[3 * 256]);
        u32x4 u4 = __builtin_nontemporal_load(&ap[4 * 256]);
        u32x4 u5 = __builtin_nontemporal_load(&ap[5 * 256]);
        u32x4 u6 = __builtin_nontemporal_load(&ap[6 * 256]);
        u32x4 u7 = __builtin_nontemporal_load(&ap[7 * 256]);
        float acc = 0.f;
        consume(u0, 0, acc); consume(u1, 1, acc); consume(u2, 2, acc); consume(u3, 3, acc);
        consume(u4, 4, acc); consume(u5, 5, acc); consume(u6, 6, acc); consume(u7, 7, acc);
        scratchB[sl * 1024 + (chunk << 8) + t8] = acc;
        __syncthreads();   // scratchB slice published; also paces waves together
      }
    }
    // ---- P4: softmax numerator + denominator partials ----
    {
      int base = (tid >> 8) * 1024 + (tid & 255);
      float e = Sv_vb + scratchB[base] + scratchB[base + 256] +
                scratchB[base + 512] + scratchB[base + 768];
      float p = (maskv != 0.f) ? __builtin_amdgcn_exp2f(e * L2E) : 0.f;
      p_lds[tid] = p;
      for (int m = 32; m; m >>= 1) p += __shfl_xor(p, m);
      if (lane == 0) red_lds[wid] = p;
    }
    __syncthreads();
    // ---- P5: context partials (enc nt-stream, 4-deep rotating prefetch) fused
    //      with gate pre/h dots; ctx reduced IN-WAVE over tec via shfl_xor.
    {
      gph = biasg_r;
      float cc0 = 0, cc1 = 0, cc2 = 0, cc3 = 0, cc4 = 0, cc5 = 0, cc6 = 0, cc7 = 0;
      auto cons = [&](u32x4 u, int s) {
        float pv = p_lds[(s << 5) + tec];
        float e0, e1, e2, e3, e4, e5, e6, e7;
        unpk(u.x, e0, e1); unpk(u.y, e2, e3);
        unpk(u.z, e4, e5); unpk(u.w, e6, e7);
        cc0 = fmaf(pv, e0, cc0); cc1 = fmaf(pv, e1, cc1);
        cc2 = fmaf(pv, e2, cc2); cc3 = fmaf(pv, e3, cc3);
        cc4 = fmaf(pv, e4, cc4); cc5 = fmaf(pv, e5, cc5);
        cc6 = fmaf(pv, e6, cc6); cc7 = fmaf(pv, e7, cc7);
      };
      u32x4 e0 = __builtin_nontemporal_load(&eB[0 << 5]);
      u32x4 e1 = __builtin_nontemporal_load(&eB[1 << 5]);
      u32x4 e2 = __builtin_nontemporal_load(&eB[2 << 5]);
      u32x4 e3 = __builtin_nontemporal_load(&eB[3 << 5]);
#pragma unroll
      for (int g = 0; g < 8; ++g) {
        // gdot chunk g: 16 iterations; g 0..3 -> wpB rows g*16.., g 4..7 -> whB
        {
          const float4* wB = (g < 4) ? wpB : whB;
          const float* xl = (g < 4) ? pre_lds : h_lds;
          const int i0 = (g & 3) * 16;
#pragma unroll
          for (int i = i0; i < i0 + 16; ++i) {
            float4 w = wB[(size_t)i << 10];
            float4 x = *(const float4*)&xl[i << 2];
            gph = fmaf(w.x, x.x, gph); gph = fmaf(w.y, x.y, gph);
            gph = fmaf(w.z, x.z, gph); gph = fmaf(w.w, x.w, gph);
          }
        }
        u32x4 c0 = e0, c1 = e1, c2 = e2, c3 = e3;
        if (g < 7) {
          const int s = g * 4 + 4;
          e0 = __builtin_nontemporal_load(&eB[(s + 0) << 5]);
          e1 = __builtin_nontemporal_load(&eB[(s + 1) << 5]);
          e2 = __builtin_nontemporal_load(&eB[(s + 2) << 5]);
          e3 = __builtin_nontemporal_load(&eB[(s + 3) << 5]);
        }
        cons(c0, g * 4 + 0); cons(c1, g * 4 + 1);
        cons(c2, g * 4 + 2); cons(c3, g * 4 + 3);
      }
      // in-wave reduction over tec (lanes 0..31 / 32..63 are independent halves)
#define REDTEC(x) { x += __shfl_xor(x, 1); x += __shfl_xor(x, 2); x += __shfl_xor(x, 4); \
                    x += __shfl_xor(x, 8); x += __shfl_xor(x, 16); }
      REDTEC(cc0) REDTEC(cc1) REDTEC(cc2) REDTEC(cc3)
      REDTEC(cc4) REDTEC(cc5) REDTEC(cc6) REDTEC(cc7)
#undef REDTEC
      if (tec == 0) {
        float* cp = &ctxp_lds[d8 << 3];
        cp[0] = cc0; cp[1] = cc1; cp[2] = cc2; cp[3] = cc3;
        cp[4] = cc4; cp[5] = cc5; cp[6] = cc6; cp[7] = cc7;
      }
    }
    __syncthreads();
    // ---- P6: softmax normalize context ----
    if (tid < 256) {
      float S = red_lds[0] + red_lds[1] + red_lds[2] + red_lds[3] +
                red_lds[4] + red_lds[5] + red_lds[6] + red_lds[7] +
                red_lds[8] + red_lds[9] + red_lds[10] + red_lds[11] +
                red_lds[12] + red_lds[13] + red_lds[14] + red_lds[15];
      ctx_lds[tid] = ctxp_lds[tid] * (1.f / S);
    }
    __syncthreads();
    // ---- P7: gates ctx-dot ----
    {
      float g = gph;
#pragma unroll 8
      for (int i = 0; i < 64; ++i) {
        float4 w = wcB[(size_t)i << 10];
        float4 x = *(const float4*)&ctx_lds[i << 2];
        g = fmaf(w.x, x.x, g); g = fmaf(w.y, x.y, g);
        g = fmaf(w.z, x.z, g); g = fmaf(w.w, x.w, g);
      }
      gates_lds[tid] = g;
    }
    __syncthreads();
    // ---- P8: LSTM pointwise ----
    if (tid < 256) {
      float ii = gates_lds[tid], ff = gates_lds[256 + tid];
      float gg = gates_lds[512 + tid], oo = gates_lds[768 + tid];
      float si = __builtin_amdgcn_rcpf(1.f + __builtin_amdgcn_exp2f(-ii * L2E));
      float sf = __builtin_amdgcn_rcpf(1.f + __builtin_amdgcn_exp2f(-ff * L2E));
      float so = __builtin_amdgcn_rcpf(1.f + __builtin_amdgcn_exp2f(-oo * L2E));
      float tg2 = 1.f - 2.f * __builtin_amdgcn_rcpf(1.f + __builtin_amdgcn_exp2f(gg * CE));
      float cn = sf * c_reg + si * tg2;
      float tc = 1.f - 2.f * __builtin_amdgcn_rcpf(1.f + __builtin_amdgcn_exp2f(cn * CE));
      c_reg = cn;
      h_lds[tid] = so * tc;
    }
    __syncthreads();
  }
  heads(999);
}

extern "C" void kernel_launch(void* const* d_in, const int* in_sizes, int n_in,
                              void* d_out, int out_size, void* d_ws, size_t ws_size,
                              hipStream_t stream) {
  const float* enc = (const float*)d_in[0];
  const float* tmel = (const float*)d_in[1];
  const float* W_enc = (const float*)d_in[2];
  const float* b_enc = (const float*)d_in[3];
  const float* W_dec = (const float*)d_in[4];
  const float* b_dec = (const float*)d_in[5];
  const float* v_w = (const float*)d_in[6];
  const float* v_b = (const float*)d_in[7];
  const float* pW1 = (const float*)d_in[8];
  const float* pb1 = (const float*)d_in[9];
  const float* pW2 = (const float*)d_in[10];
  const float* pb2 = (const float*)d_in[11];
  const float* W_ih = (const float*)d_in[12];
  const float* W_hh = (const float*)d_in[13];
  const float* b_ih = (const float*)d_in[14];
  const float* b_hh = (const float*)d_in[15];
  const float* mel_W = (const float*)d_in[16];
  const float* mel_b = (const float*)d_in[17];
  const float* stop_W = (const float*)d_in[18];
  const float* stop_b = (const float*)d_in[19];
  const float* emask = (const float*)d_in[20];

  if (ws_size < WS_NEED) return;  // fail-visible rather than corrupt

  char* ws = (char*)d_ws;
  unsigned* attnR = (unsigned*)(ws + OFF_ATTNR);
  u32x4* encP = (u32x4*)(ws + OFF_ENCP);
  unsigned short* pre2 = (unsigned short*)(ws + OFF_PRE2);
  float* WdT = (float*)(ws + OFF_WDT);
  float* WhT = (float*)(ws + OFF_WHT);
  float* WcT = (float*)(ws + OFF_WCT);
  float* WpT = (float*)(ws + OFF_WPT);
  float* biasG = (float*)(ws + OFF_BIASG);

  conv_encP<<<8192, 256, 0, stream>>>(enc, encP);
  prep_w2<<<3332, 256, 0, stream>>>(W_dec, W_hh, W_ih, b_ih, b_hh, WdT, WhT, WcT, WpT, biasG);
  attn_gemm<<<1024, 256, 0, stream>>>(enc, W_enc, b_enc, attnR);
  prenet_fused<<<1000, 256, 0, stream>>>(tmel, pW1, pb1, pW2, pb2, pre2);
  decoder_one<<<64, 1024, 0, stream>>>(
      (const u32x4*)attnR, (const u32x4*)encP, pre2,
      (const float4*)WdT, (const float4*)WhT, (const float4*)WcT, (const float4*)WpT,
      biasG, b_dec, v_w, v_b, emask, mel_W, mel_b, stop_W, stop_b, (float*)d_out);
}

// Round 7
// 172084.204 us; speedup vs baseline: 1.7758x; 1.7758x over previous
//
#include <hip/hip_runtime.h>
#include <hip/hip_bf16.h>

#define NMEL 80

typedef unsigned u32x4 __attribute__((ext_vector_type(4)));

__device__ __forceinline__ float bf2f(unsigned short u) {
  unsigned v = ((unsigned)u) << 16; float f; __builtin_memcpy(&f, &v, 4); return f;
}
__device__ __forceinline__ unsigned short f2bf_u(float f) {
  __hip_bfloat16 h = __float2bfloat16(f); unsigned short u; __builtin_memcpy(&u, &h, 2); return u;
}
__device__ __forceinline__ void unpk(unsigned u, float& lo, float& hi) {
  unsigned l = u << 16, h = u & 0xffff0000u;
  __builtin_memcpy(&lo, &l, 4); __builtin_memcpy(&hi, &h, 4);
}

// ---------------- workspace layout (bytes) ----------------
constexpr size_t OFF_ATTNR = 0;                                  // bf16 pairs, attn_gemm layout
constexpr size_t SZ_ATTNR = (size_t)64 * 1024 * 256 * 2;         // 33,554,432
constexpr size_t OFF_ENCP = OFF_ATTNR + SZ_ATTNR;                // uint4[(b*32+d8)*1024+te]
constexpr size_t SZ_ENCP = (size_t)64 * 1024 * 256 * 2;          // 33,554,432
constexpr size_t OFF_PRE2 = OFF_ENCP + SZ_ENCP;                  // bf16 [64000][256]
constexpr size_t SZ_PRE2 = (size_t)64000 * 256 * 2;
constexpr size_t OFF_WDT = OFF_PRE2 + SZ_PRE2;                   // f32 float4[kq][256]
constexpr size_t SZ_WDT = (size_t)65536 * 4;
constexpr size_t OFF_WHT = OFF_WDT + SZ_WDT;                     // f32 float4[kq][1024]
constexpr size_t SZ_W1M = (size_t)262144 * 4;
constexpr size_t OFF_WCT = OFF_WHT + SZ_W1M;
constexpr size_t OFF_WPT = OFF_WCT + SZ_W1M;
constexpr size_t OFF_BIASG = OFF_WPT + SZ_W1M;                   // f32 [1024]
constexpr size_t SZ_BIASG = 1024 * 4;
constexpr size_t WS_NEED = OFF_BIASG + SZ_BIASG;                 // ~98.5 MiB

// ---------------- enc fp32 -> bf16-packed [b][d8][te] uint4 ----------------
__global__ __launch_bounds__(256) void conv_encP(const float* __restrict__ enc,
                                                 u32x4* __restrict__ encP) {
  int idx = blockIdx.x * 256 + threadIdx.x;      // 64*32*1024 = 2,097,152 exact
  int b = idx >> 15, r = idx & 32767;
  int d8 = r >> 10, te = r & 1023;
  const float4* src = (const float4*)(enc + ((size_t)(b * 1024 + te)) * 256 + d8 * 8);
  float4 x0 = src[0], x1 = src[1];
  u32x4 o;
  o.x = (unsigned)f2bf_u(x0.x) | ((unsigned)f2bf_u(x0.y) << 16);
  o.y = (unsigned)f2bf_u(x0.z) | ((unsigned)f2bf_u(x0.w) << 16);
  o.z = (unsigned)f2bf_u(x1.x) | ((unsigned)f2bf_u(x1.y) << 16);
  o.w = (unsigned)f2bf_u(x1.z) | ((unsigned)f2bf_u(x1.w) << 16);
  encP[((size_t)(b * 32 + d8)) * 1024 + te] = o;
}

// ---------------- weight re-layout (fp32, row-coalesced float4) ----------------
__global__ __launch_bounds__(256) void prep_w2(
    const float* __restrict__ W_dec, const float* __restrict__ W_hh,
    const float* __restrict__ W_ih, const float* __restrict__ b_ih,
    const float* __restrict__ b_hh,
    float* __restrict__ WdT, float* __restrict__ WhT,
    float* __restrict__ WcT, float* __restrict__ WpT, float* __restrict__ biasG) {
  int idx = blockIdx.x * 256 + threadIdx.x;
  if (idx < 65536) {                       // WdT[kq][a][q] = W_dec[a][4kq+q]
    int q = idx & 3, a = (idx >> 2) & 255, kq = idx >> 10;
    WdT[idx] = W_dec[(size_t)a * 256 + kq * 4 + q];
  } else if (idx < 327680) {               // WhT[kq][g][q] = W_hh[g][4kq+q]
    int i = idx - 65536;
    int q = i & 3, g = (i >> 2) & 1023, kq = i >> 12;
    WhT[i] = W_hh[(size_t)g * 256 + kq * 4 + q];
  } else if (idx < 589824) {               // WcT: ctx part of W_ih (cols 256..511)
    int i = idx - 327680;
    int q = i & 3, g = (i >> 2) & 1023, kq = i >> 12;
    WcT[i] = W_ih[(size_t)g * 512 + 256 + kq * 4 + q];
  } else if (idx < 851968) {               // WpT: prenet part of W_ih (cols 0..255)
    int i = idx - 589824;
    int q = i & 3, g = (i >> 2) & 1023, kq = i >> 12;
    WpT[i] = W_ih[(size_t)g * 512 + kq * 4 + q];
  } else if (idx < 852992) {
    int g = idx - 851968;
    biasG[g] = b_ih[g] + b_hh[g];
  }
}

// ---------------- attn_enc GEMM -> bf16 layout attnR (unchanged) ----------------
__global__ __launch_bounds__(256) void attn_gemm(const float* __restrict__ enc,
                                                 const float* __restrict__ W_enc,
                                                 const float* __restrict__ b_enc,
                                                 unsigned* __restrict__ attnR) {
  __shared__ unsigned short Alds[64 * 260];
  const int tid = threadIdx.x;
  const int row0 = blockIdx.x * 64;
  const int wv = tid >> 6, lane = tid & 63, nb = wv * 64;
  for (int idx = tid; idx < 64 * 256; idx += 256) {
    int r = idx >> 8, k = idx & 255;
    Alds[r * 260 + k] = f2bf_u(enc[(size_t)(row0 + r) * 256 + k]);
  }
  __syncthreads();
  float acc[64];
#pragma unroll
  for (int n = 0; n < 64; ++n) acc[n] = b_enc[nb + n];
  for (int k8 = 0; k8 < 256; k8 += 8) {
    ushort4 ua = *(const ushort4*)&Alds[lane * 260 + k8];
    ushort4 ub = *(const ushort4*)&Alds[lane * 260 + k8 + 4];
    float a0 = bf2f(ua.x), a1 = bf2f(ua.y), a2 = bf2f(ua.z), a3 = bf2f(ua.w);
    float a4 = bf2f(ub.x), a5 = bf2f(ub.y), a6 = bf2f(ub.z), a7 = bf2f(ub.w);
#pragma unroll
    for (int n = 0; n < 64; ++n) {
      const float4* wp = (const float4*)(W_enc + (size_t)(nb + n) * 256 + k8);
      float4 w0 = wp[0], w1 = wp[1];
      acc[n] = fmaf(a0, w0.x, acc[n]); acc[n] = fmaf(a1, w0.y, acc[n]);
      acc[n] = fmaf(a2, w0.z, acc[n]); acc[n] = fmaf(a3, w0.w, acc[n]);
      acc[n] = fmaf(a4, w1.x, acc[n]); acc[n] = fmaf(a5, w1.y, acc[n]);
      acc[n] = fmaf(a6, w1.z, acc[n]); acc[n] = fmaf(a7, w1.w, acc[n]);
    }
  }
  const float CE = 2.8853900817779268f;  // 2*log2(e)
  const int b = row0 >> 10;
  const int te_g = (row0 & 1023) + lane;
  const int sl = te_g >> 8, te_loc = te_g & 255;
#pragma unroll
  for (int n = 0; n < 64; n += 2) {
    int a = nb + n;
    unsigned pair = (unsigned)f2bf_u(acc[n] * CE) | ((unsigned)f2bf_u(acc[n + 1] * CE) << 16);
    size_t u4 = ((((size_t)(b * 4 + sl) * 4 + (a >> 6)) * 8 + ((a >> 3) & 7)) * 256 + te_loc);
    attnR[u4 * 4 + ((a & 7) >> 1)] = pair;
  }
}

// ---------------- fused prenet (unchanged) ----------------
__global__ __launch_bounds__(256) void prenet_fused(const float* __restrict__ tmel,
                                                    const float* __restrict__ W1,
                                                    const float* __restrict__ b1,
                                                    const float* __restrict__ W2,
                                                    const float* __restrict__ b2,
                                                    unsigned short* __restrict__ pre2) {
  __shared__ unsigned short Alds[64 * 260];
  const int tid = threadIdx.x;
  const int row0 = blockIdx.x * 64;
  const int wv = tid >> 6, lane = tid & 63, nb = wv * 64;
  for (int idx = tid; idx < 64 * 80; idx += 256) {
    int r = idx / 80, k = idx - r * 80;
    int R = row0 + r;
    float v = (R % 1000 != 0) ? tmel[(size_t)(R - 1) * NMEL + k] : 0.f;
    Alds[r * 260 + k] = f2bf_u(v);
  }
  __syncthreads();
  float acc[64];
#pragma unroll
  for (int n = 0; n < 64; ++n) acc[n] = b1[nb + n];
  for (int k8 = 0; k8 < 80; k8 += 8) {
    ushort4 ua = *(const ushort4*)&Alds[lane * 260 + k8];
    ushort4 ub = *(const ushort4*)&Alds[lane * 260 + k8 + 4];
    float a0 = bf2f(ua.x), a1 = bf2f(ua.y), a2 = bf2f(ua.z), a3 = bf2f(ua.w);
    float a4 = bf2f(ub.x), a5 = bf2f(ub.y), a6 = bf2f(ub.z), a7 = bf2f(ub.w);
#pragma unroll
    for (int n = 0; n < 64; ++n) {
      const float4* wp = (const float4*)(W1 + (size_t)(nb + n) * 80 + k8);
      float4 w0 = wp[0], w1 = wp[1];
      acc[n] = fmaf(a0, w0.x, acc[n]); acc[n] = fmaf(a1, w0.y, acc[n]);
      acc[n] = fmaf(a2, w0.z, acc[n]); acc[n] = fmaf(a3, w0.w, acc[n]);
      acc[n] = fmaf(a4, w1.x, acc[n]); acc[n] = fmaf(a5, w1.y, acc[n]);
      acc[n] = fmaf(a6, w1.z, acc[n]); acc[n] = fmaf(a7, w1.w, acc[n]);
    }
  }
  __syncthreads();
#pragma unroll
  for (int n = 0; n < 64; ++n) Alds[lane * 260 + nb + n] = f2bf_u(fmaxf(acc[n], 0.f));
  __syncthreads();
#pragma unroll
  for (int n = 0; n < 64; ++n) acc[n] = b2[nb + n];
  for (int k8 = 0; k8 < 256; k8 += 8) {
    ushort4 ua = *(const ushort4*)&Alds[lane * 260 + k8];
    ushort4 ub = *(const ushort4*)&Alds[lane * 260 + k8 + 4];
    float a0 = bf2f(ua.x), a1 = bf2f(ua.y), a2 = bf2f(ua.z), a3 = bf2f(ua.w);
    float a4 = bf2f(ub.x), a5 = bf2f(ub.y), a6 = bf2f(ub.z), a7 = bf2f(ub.w);
#pragma unroll
    for (int n = 0; n < 64; ++n) {
      const float4* wp = (const float4*)(W2 + (size_t)(nb + n) * 256 + k8);
      float4 w0 = wp[0], w1 = wp[1];
      acc[n] = fmaf(a0, w0.x, acc[n]); acc[n] = fmaf(a1, w0.y, acc[n]);
      acc[n] = fmaf(a2, w0.z, acc[n]); acc[n] = fmaf(a3, w0.w, acc[n]);
      acc[n] = fmaf(a4, w1.x, acc[n]); acc[n] = fmaf(a5, w1.y, acc[n]);
      acc[n] = fmaf(a6, w1.z, acc[n]); acc[n] = fmaf(a7, w1.w, acc[n]);
    }
  }
  __syncthreads();
#pragma unroll
  for (int n = 0; n < 64; ++n) Alds[lane * 260 + nb + n] = f2bf_u(fmaxf(acc[n], 0.f));
  __syncthreads();
  for (int idx = tid; idx < 64 * 128; idx += 256) {
    int r = idx >> 7, k2 = (idx & 127) * 2;
    unsigned pair = (unsigned)Alds[r * 260 + k2] | ((unsigned)Alds[r * 260 + k2 + 1] << 16);
    *(unsigned*)(pre2 + (size_t)(row0 + r) * 256 + k2) = pair;
  }
}

// ---------------- single-WG-per-batch persistent decoder ----------------
// 64 WGs x 1024 threads. All exchange via LDS + __syncthreads.
// NO nontemporal hints: the 67 MB attnR+encP working set must be retained in the
// 256 MB Infinity Cache across steps. Rounds 1-5 used __builtin_nontemporal_load,
// which marked the stream evict-first -> 77 MB/step re-fetched from HBM at the
// ~490 GB/s 64 CUs can pull = ~157 us/step (the whole runtime).
__global__ __launch_bounds__(1024) void decoder_one(
    const u32x4* __restrict__ attnR, const u32x4* __restrict__ encP,
    const unsigned short* __restrict__ pre2,
    const float4* __restrict__ WdT, const float4* __restrict__ WhT,
    const float4* __restrict__ WcT, const float4* __restrict__ WpT,
    const float* __restrict__ biasG,
    const float* __restrict__ b_dec, const float* __restrict__ v_w,
    const float* __restrict__ v_b, const float* __restrict__ enc_mask,
    const float* __restrict__ mel_W, const float* __restrict__ mel_b,
    const float* __restrict__ stop_W, const float* __restrict__ stop_b,
    float* __restrict__ out) {
  __shared__ __align__(16) float scratchB[8448];   // 33 KB: energy[4096] / ctx partials [256][33]
  __shared__ __align__(16) float p_lds[1024];
  __shared__ __align__(16) float gates_lds[1024];
  __shared__ __align__(16) float h_lds[256];
  __shared__ __align__(16) float ctx_lds[256];
  __shared__ __align__(16) float pre_lds[256];
  __shared__ __align__(16) float dec_lds[256];
  __shared__ __align__(16) float v2_lds[256];
  __shared__ float red_lds[16];

  const int tid = threadIdx.x;
  const int b = blockIdx.x;                 // one batch per WG
  const int t8 = tid & 255, chunk = tid >> 8;
  const int lane = tid & 63, wid = tid >> 6;
  const int d8 = tid >> 5, tec = tid & 31;  // context-phase mapping
  const float CE = 2.8853900817779268f;     // 2*log2(e)
  const float L2E = 1.4426950408889634f;    // log2(e)

  // ---- init ----
  if (tid < 256) {
    h_lds[tid] = 0.f;
    float v = v_w[tid];
    v2_lds[tid] = -2.f * v;
    for (int m = 32; m; m >>= 1) v += __shfl_xor(v, m);
    if (lane == 0) red_lds[wid] = v;
  }
  float c_reg = 0.f;
  const float maskv = enc_mask[b * 1024 + tid];
  const float bdec_r = (tid < 256) ? b_dec[tid] : 0.f;
  const float biasg_r = biasG[tid];
  const float melb_r = (tid < 640 && (tid & 7) == 0) ? mel_b[tid >> 3] : 0.f;
  float stopw[8];
  if (wid == 11) {
#pragma unroll
    for (int i = 0; i < 8; ++i) stopw[i] = stop_W[lane * 8 + i];
  }
  __syncthreads();
  const float Sv_vb = red_lds[0] + red_lds[1] + red_lds[2] + red_lds[3] + v_b[0];
  const float stopb0 = stop_b[0];

  const u32x4* aB = attnR + (size_t)b * 32768 + chunk * 2048 + t8;
  const u32x4* eB = encP + ((size_t)(b * 32 + d8)) * 1024 + tec;
  const float4* wdB = WdT + chunk * 16 * 256 + t8;
  const float4* whB = WhT + tid;
  const float4* wcB = WcT + tid;
  const float4* wpB = WpT + tid;
  const unsigned short* pre2_b = pre2 + (size_t)b * 256000;
  float* outm = out + (size_t)b * 80000;
  float* outs = out + (size_t)5120000 + b * 1000;

  auto heads = [&](int ith) {  // mel + stop for step ith (uses h_lds, ctx_lds)
    if (tid < 640) {
      const int m = tid >> 3, q = tid & 7;
      float acc = melb_r;
      const float4* wm = (const float4*)(mel_W + (size_t)m * 512 + q * 64);
      const float4* xp = (q < 4) ? (const float4*)&h_lds[q * 64]
                                 : (const float4*)&ctx_lds[(q - 4) * 64];
#pragma unroll
      for (int i = 0; i < 16; ++i) {
        float4 w = wm[i]; float4 x = xp[i];
        acc = fmaf(w.x, x.x, acc); acc = fmaf(w.y, x.y, acc);
        acc = fmaf(w.z, x.z, acc); acc = fmaf(w.w, x.w, acc);
      }
      acc += __shfl_xor(acc, 1); acc += __shfl_xor(acc, 2); acc += __shfl_xor(acc, 4);
      if (q == 0) outm[ith * 80 + m] = acc;
    } else if (wid == 11) {
      float acc = 0.f;
#pragma unroll
      for (int i = 0; i < 8; ++i) {
        int cc = lane * 8 + i;
        float x = (cc < 256) ? h_lds[cc] : ctx_lds[cc - 256];
        acc = fmaf(stopw[i], x, acc);
      }
      for (int m = 32; m; m >>= 1) acc += __shfl_xor(acc, m);
      if (lane == 0) outs[ith] = acc + stopb0;
    }
  };

  float gph = 0.f;  // gates partial (bias + pre-dot + h-dot), carried P5 -> P7

  for (int it = 0; it < 1000; ++it) {
    // ---- P1: attn_dec partials (uses h from prev step) + pre load + heads(it-1) ----
    {
      float acc = 0.f;
#pragma unroll
      for (int i = 0; i < 16; ++i) {
        float4 w = wdB[(size_t)i << 8];
        float4 h4 = *(const float4*)&h_lds[chunk * 64 + i * 4];
        acc = fmaf(w.x, h4.x, acc); acc = fmaf(w.y, h4.y, acc);
        acc = fmaf(w.z, h4.z, acc); acc = fmaf(w.w, h4.w, acc);
      }
      scratchB[(chunk << 8) + t8] = acc;
      if (tid < 256) pre_lds[tid] = bf2f(pre2_b[it * 256 + tid]);
      if (it > 0) heads(it - 1);
    }
    __syncthreads();
    // ---- P2: dec reduce (pre-scaled by 2*log2e) ----
    if (tid < 256)
      dec_lds[tid] = (bdec_r + scratchB[tid] + scratchB[256 + tid] +
                      scratchB[512 + tid] + scratchB[768 + tid]) * CE;
    __syncthreads();
    // ---- P3: energy partials (attn stream, L3-resident) ----
#pragma unroll 1
    for (int sl = 0; sl < 4; ++sl) {
      float acc = 0.f;
#pragma unroll
      for (int j = 0; j < 8; ++j) {
        u32x4 u = aB[sl * 8192 + j * 256];
        int ab = (chunk << 6) + (j << 3);
        float4 d0 = *(const float4*)&dec_lds[ab];
        float4 d1 = *(const float4*)&dec_lds[ab + 4];
        float4 v0 = *(const float4*)&v2_lds[ab];
        float4 v1 = *(const float4*)&v2_lds[ab + 4];
        float t0, t1, t2, t3, t4, t5, t6, t7;
        unpk(u.x, t0, t1); unpk(u.y, t2, t3); unpk(u.z, t4, t5); unpk(u.w, t6, t7);
        acc = fmaf(v0.x, __builtin_amdgcn_rcpf(1.f + __builtin_amdgcn_exp2f(t0 + d0.x)), acc);
        acc = fmaf(v0.y, __builtin_amdgcn_rcpf(1.f + __builtin_amdgcn_exp2f(t1 + d0.y)), acc);
        acc = fmaf(v0.z, __builtin_amdgcn_rcpf(1.f + __builtin_amdgcn_exp2f(t2 + d0.z)), acc);
        acc = fmaf(v0.w, __builtin_amdgcn_rcpf(1.f + __builtin_amdgcn_exp2f(t3 + d0.w)), acc);
        acc = fmaf(v1.x, __builtin_amdgcn_rcpf(1.f + __builtin_amdgcn_exp2f(t4 + d1.x)), acc);
        acc = fmaf(v1.y, __builtin_amdgcn_rcpf(1.f + __builtin_amdgcn_exp2f(t5 + d1.y)), acc);
        acc = fmaf(v1.z, __builtin_amdgcn_rcpf(1.f + __builtin_amdgcn_exp2f(t6 + d1.z)), acc);
        acc = fmaf(v1.w, __builtin_amdgcn_rcpf(1.f + __builtin_amdgcn_exp2f(t7 + d1.w)), acc);
      }
      scratchB[sl * 1024 + (chunk << 8) + t8] = acc;
    }
    __syncthreads();
    // ---- P4: softmax numerator + denominator partials ----
    {
      int base = (tid >> 8) * 1024 + (tid & 255);
      float e = Sv_vb + scratchB[base] + scratchB[base + 256] +
                scratchB[base + 512] + scratchB[base + 768];
      float p = (maskv != 0.f) ? __builtin_amdgcn_exp2f(e * L2E) : 0.f;
      p_lds[tid] = p;
      for (int m = 32; m; m >>= 1) p += __shfl_xor(p, m);
      if (lane == 0) red_lds[wid] = p;
    }
    __syncthreads();
    // ---- P5: context partials (enc stream, L3-resident) FUSED with gates pre/h dots ----
    {
      gph = biasg_r;
      float cc0 = 0, cc1 = 0, cc2 = 0, cc3 = 0, cc4 = 0, cc5 = 0, cc6 = 0, cc7 = 0;
      u32x4 eb[8];
      auto issueQ = [&](int q0) {
#pragma unroll
        for (int t = 0; t < 8; ++t)
          eb[t] = eB[((q0 << 3) + t) << 5];
      };
      auto consumeQ = [&](int q0) {
#pragma unroll
        for (int t = 0; t < 8; ++t) {
          float pv = p_lds[((((q0 << 3) + t) << 5)) + tec];
          float e0, e1, e2, e3, e4, e5, e6, e7;
          unpk(eb[t].x, e0, e1); unpk(eb[t].y, e2, e3);
          unpk(eb[t].z, e4, e5); unpk(eb[t].w, e6, e7);
          cc0 = fmaf(pv, e0, cc0); cc1 = fmaf(pv, e1, cc1);
          cc2 = fmaf(pv, e2, cc2); cc3 = fmaf(pv, e3, cc3);
          cc4 = fmaf(pv, e4, cc4); cc5 = fmaf(pv, e5, cc5);
          cc6 = fmaf(pv, e6, cc6); cc7 = fmaf(pv, e7, cc7);
        }
      };
      auto gdot = [&](const float4* __restrict__ wB, const float* __restrict__ xl, int i0) {
#pragma unroll 8
        for (int i = i0; i < i0 + 32; ++i) {
          float4 w = wB[(size_t)i << 10];
          float4 x = *(const float4*)&xl[i << 2];
          gph = fmaf(w.x, x.x, gph); gph = fmaf(w.y, x.y, gph);
          gph = fmaf(w.z, x.z, gph); gph = fmaf(w.w, x.w, gph);
        }
      };
      issueQ(0); gdot(wpB, pre_lds, 0);  consumeQ(0);
      issueQ(1); gdot(wpB, pre_lds, 32); consumeQ(1);
      issueQ(2); gdot(whB, h_lds, 0);    consumeQ(2);
      issueQ(3); gdot(whB, h_lds, 32);   consumeQ(3);
      float* cb = &scratchB[(d8 << 3) * 33 + tec];   // rows [d][33] (padded: no bank conflict)
      cb[0] = cc0; cb[33] = cc1; cb[66] = cc2; cb[99] = cc3;
      cb[132] = cc4; cb[165] = cc5; cb[198] = cc6; cb[231] = cc7;
    }
    __syncthreads();
    // ---- P6: context reduce + softmax normalize ----
    if (tid < 256) {
      float S = red_lds[0] + red_lds[1] + red_lds[2] + red_lds[3] +
                red_lds[4] + red_lds[5] + red_lds[6] + red_lds[7] +
                red_lds[8] + red_lds[9] + red_lds[10] + red_lds[11] +
                red_lds[12] + red_lds[13] + red_lds[14] + red_lds[15];
      float rS = 1.f / S;
      float s = 0.f;
      const float* row = &scratchB[tid * 33];
#pragma unroll
      for (int t = 0; t < 32; ++t) s += row[t];
      ctx_lds[tid] = s * rS;
    }
    __syncthreads();
    // ---- P7: gates ctx-dot ----
    {
      float g = gph;
#pragma unroll 8
      for (int i = 0; i < 64; ++i) {
        float4 w = wcB[(size_t)i << 10];
        float4 x = *(const float4*)&ctx_lds[i << 2];
        g = fmaf(w.x, x.x, g); g = fmaf(w.y, x.y, g);
        g = fmaf(w.z, x.z, g); g = fmaf(w.w, x.w, g);
      }
      gates_lds[tid] = g;
    }
    __syncthreads();
    // ---- P8: LSTM pointwise ----
    if (tid < 256) {
      float ii = gates_lds[tid], ff = gates_lds[256 + tid];
      float gg = gates_lds[512 + tid], oo = gates_lds[768 + tid];
      float si = __builtin_amdgcn_rcpf(1.f + __builtin_amdgcn_exp2f(-ii * L2E));
      float sf = __builtin_amdgcn_rcpf(1.f + __builtin_amdgcn_exp2f(-ff * L2E));
      float so = __builtin_amdgcn_rcpf(1.f + __builtin_amdgcn_exp2f(-oo * L2E));
      float tg2 = 1.f - 2.f * __builtin_amdgcn_rcpf(1.f + __builtin_amdgcn_exp2f(gg * CE));
      float cn = sf * c_reg + si * tg2;
      float tc = 1.f - 2.f * __builtin_amdgcn_rcpf(1.f + __builtin_amdgcn_exp2f(cn * CE));
      c_reg = cn;
      h_lds[tid] = so * tc;
    }
    __syncthreads();
  }
  heads(999);
}

extern "C" void kernel_launch(void* const* d_in, const int* in_sizes, int n_in,
                              void* d_out, int out_size, void* d_ws, size_t ws_size,
                              hipStream_t stream) {
  const float* enc = (const float*)d_in[0];
  const float* tmel = (const float*)d_in[1];
  const float* W_enc = (const float*)d_in[2];
  const float* b_enc = (const float*)d_in[3];
  const float* W_dec = (const float*)d_in[4];
  const float* b_dec = (const float*)d_in[5];
  const float* v_w = (const float*)d_in[6];
  const float* v_b = (const float*)d_in[7];
  const float* pW1 = (const float*)d_in[8];
  const float* pb1 = (const float*)d_in[9];
  const float* pW2 = (const float*)d_in[10];
  const float* pb2 = (const float*)d_in[11];
  const float* W_ih = (const float*)d_in[12];
  const float* W_hh = (const float*)d_in[13];
  const float* b_ih = (const float*)d_in[14];
  const float* b_hh = (const float*)d_in[15];
  const float* mel_W = (const float*)d_in[16];
  const float* mel_b = (const float*)d_in[17];
  const float* stop_W = (const float*)d_in[18];
  const float* stop_b = (const float*)d_in[19];
  const float* emask = (const float*)d_in[20];

  if (ws_size < WS_NEED) return;  // fail-visible rather than corrupt

  char* ws = (char*)d_ws;
  unsigned* attnR = (unsigned*)(ws + OFF_ATTNR);
  u32x4* encP = (u32x4*)(ws + OFF_ENCP);
  unsigned short* pre2 = (unsigned short*)(ws + OFF_PRE2);
  float* WdT = (float*)(ws + OFF_WDT);
  float* WhT = (float*)(ws + OFF_WHT);
  float* WcT = (float*)(ws + OFF_WCT);
  float* WpT = (float*)(ws + OFF_WPT);
  float* biasG = (float*)(ws + OFF_BIASG);

  conv_encP<<<8192, 256, 0, stream>>>(enc, encP);
  prep_w2<<<3332, 256, 0, stream>>>(W_dec, W_hh, W_ih, b_ih, b_hh, WdT, WhT, WcT, WpT, biasG);
  attn_gemm<<<1024, 256, 0, stream>>>(enc, W_enc, b_enc, attnR);
  prenet_fused<<<1000, 256, 0, stream>>>(tmel, pW1, pb1, pW2, pb2, pre2);
  decoder_one<<<64, 1024, 0, stream>>>(
      (const u32x4*)attnR, (const u32x4*)encP, pre2,
      (const float4*)WdT, (const float4*)WhT, (const float4*)WcT, (const float4*)WpT,
      biasG, b_dec, v_w, v_b, emask, mel_W, mel_b, stop_W, stop_b, (float*)d_out);
}